// Round 4
// baseline (149.966 us; speedup 1.0000x reference)
//
#include <hip/hip_runtime.h>

// PooledSSIMLoss: x,y (16,3,512,512) fp32, 11x11 VALID box filters,
// SSIM map (48,502,502) -> scalar 1 - mean.
//
// R4: barrier-free. 1 wave (64 threads) per block; wave owns a full 512-col
// strip of SEG=8 output rows, 8 cols/lane. Vertical running sums in regs;
// horizontal 11-tap via wave-private LDS exchange (in-order DS within a wave
// => no s_barrier needed). H stored lo/hi-quad split so every ds_write_b128 /
// ds_read_b128 is lane-contiguous (conflict-free). Global loads pipelined one
// row ahead. SSIM evaluated in the 121^2-scaled domain (no per-quantity
// INV121 scaling).

#define WIN     11
#define IMG     512
#define PLSZ    (IMG * IMG)
#define OUTW    502
#define SEG     8
#define NSEG    63             // ceil(502/8)
#define NPLANES 48
#define NPART   (NSEG * NPLANES)   // 3024

#define C1S   1.4641f          // (0.01)^2 * 121^2
#define C2S   13.1769f         // (0.03)^2 * 121^2
#define EPS4  2.1434881f       // 1e-8 * 121^4

__global__ __launch_bounds__(64) void ssim_zero(double* acc) {
    if (threadIdx.x == 0) acc[0] = 0.0;
}

__global__ __launch_bounds__(64) void ssim_main(const float* __restrict__ x,
                                                const float* __restrict__ y,
                                                double* __restrict__ part,
                                                int mode) {
    // H[q][0][4L..4L+3] = V_q cols 8L..8L+3 ; H[q][1][4L..] = cols 8L+4..8L+7
    // 264: 256 + 8 zero pad (cols >= 512 for lanes 62/63 neighbor reads)
    __shared__ __align__(16) float H[5][2][264];

    const int lane  = threadIdx.x;       // 0..63
    const int seg   = blockIdx.x;        // 0..62
    const int plane = blockIdx.y;        // 0..47
    const int o0    = seg * SEG;
    const int o1    = (o0 + SEG < OUTW) ? (o0 + SEG) : OUTW;
    const int r0    = o0;
    const int r1    = o1 + WIN - 2;      // <= 511
    const int c0    = 8 * lane;

    // zero the pad quads once (reads happen >=10 DS-ordered iterations later)
    if (lane < 20) {
        const int q = lane >> 2, rem = lane & 3;
        *(float4*)&H[q][rem >> 1][256 + ((rem & 1) << 2)] =
            make_float4(0.f, 0.f, 0.f, 0.f);
    }

    const float* xp = x + plane * PLSZ;
    const float* yp = y + plane * PLSZ;

    float Vx[8]  = {0,0,0,0,0,0,0,0};
    float Vy[8]  = {0,0,0,0,0,0,0,0};
    float Vxx[8] = {0,0,0,0,0,0,0,0};
    float Vyy[8] = {0,0,0,0,0,0,0,0};
    float Vxy[8] = {0,0,0,0,0,0,0,0};

    const float4 z4 = make_float4(0.f, 0.f, 0.f, 0.f);
    float4 nx0, nx1, ny0, ny1;                       // current new row (r)
    float4 nX0 = z4, nX1 = z4, nY0 = z4, nY1 = z4;   // inflight new (r+1)
    float4 ox0 = z4, ox1 = z4, oy0 = z4, oy1 = z4;   // current old (r-11)
    float4 oX0 = z4, oX1 = z4, oY0 = z4, oY1 = z4;   // inflight old (r-10)

    {
        const float4* px = (const float4*)(xp + r0 * IMG + c0);
        const float4* py = (const float4*)(yp + r0 * IMG + c0);
        nx0 = px[0]; nx1 = px[1]; ny0 = py[0]; ny1 = py[1];
    }

    float lsum = 0.f;

    for (int r = r0; r <= r1; ++r) {
        // ---- issue loads for iteration r+1 (consumed next iter) ----
        const int rn = r + 1;
        if (rn <= r1) {
            const float4* px = (const float4*)(xp + rn * IMG + c0);
            const float4* py = (const float4*)(yp + rn * IMG + c0);
            nX0 = px[0]; nX1 = px[1]; nY0 = py[0]; nY1 = py[1];
            const int ro = rn - WIN;                 // old row for iter r+1
            if (ro >= r0) {
                const float4* qx = (const float4*)(xp + ro * IMG + c0);
                const float4* qy = (const float4*)(yp + ro * IMG + c0);
                oX0 = qx[0]; oX1 = qx[1]; oY0 = qy[0]; oY1 = qy[1];
            }
        }

        // ---- vertical running sums: add new row r ----
        {
            const float xn[8] = {nx0.x,nx0.y,nx0.z,nx0.w, nx1.x,nx1.y,nx1.z,nx1.w};
            const float yn[8] = {ny0.x,ny0.y,ny0.z,ny0.w, ny1.x,ny1.y,ny1.z,ny1.w};
#pragma unroll
            for (int j = 0; j < 8; ++j) {
                Vx[j] += xn[j];
                Vy[j] += yn[j];
                Vxx[j] = fmaf(xn[j], xn[j], Vxx[j]);
                Vyy[j] = fmaf(yn[j], yn[j], Vyy[j]);
                Vxy[j] = fmaf(xn[j], yn[j], Vxy[j]);
            }
        }
        // ---- subtract old row r-11 ----
        if (r - r0 >= WIN) {
            const float xo[8] = {ox0.x,ox0.y,ox0.z,ox0.w, ox1.x,ox1.y,ox1.z,ox1.w};
            const float yo[8] = {oy0.x,oy0.y,oy0.z,oy0.w, oy1.x,oy1.y,oy1.z,oy1.w};
#pragma unroll
            for (int j = 0; j < 8; ++j) {
                Vx[j] -= xo[j];
                Vy[j] -= yo[j];
                Vxx[j] = fmaf(-xo[j], xo[j], Vxx[j]);
                Vyy[j] = fmaf(-yo[j], yo[j], Vyy[j]);
                Vxy[j] = fmaf(-xo[j], yo[j], Vxy[j]);
            }
        }

        // ---- emission: horizontal 11-tap + SSIM for output row r-10 ----
        if (r - r0 >= WIN - 1) {
            __builtin_amdgcn_wave_barrier();
            ((float4*)&H[0][0][4 * lane])[0] = make_float4(Vx[0],  Vx[1],  Vx[2],  Vx[3]);
            ((float4*)&H[0][1][4 * lane])[0] = make_float4(Vx[4],  Vx[5],  Vx[6],  Vx[7]);
            ((float4*)&H[1][0][4 * lane])[0] = make_float4(Vy[0],  Vy[1],  Vy[2],  Vy[3]);
            ((float4*)&H[1][1][4 * lane])[0] = make_float4(Vy[4],  Vy[5],  Vy[6],  Vy[7]);
            ((float4*)&H[2][0][4 * lane])[0] = make_float4(Vxx[0], Vxx[1], Vxx[2], Vxx[3]);
            ((float4*)&H[2][1][4 * lane])[0] = make_float4(Vxx[4], Vxx[5], Vxx[6], Vxx[7]);
            ((float4*)&H[3][0][4 * lane])[0] = make_float4(Vyy[0], Vyy[1], Vyy[2], Vyy[3]);
            ((float4*)&H[3][1][4 * lane])[0] = make_float4(Vyy[4], Vyy[5], Vyy[6], Vyy[7]);
            ((float4*)&H[4][0][4 * lane])[0] = make_float4(Vxy[0], Vxy[1], Vxy[2], Vxy[3]);
            ((float4*)&H[4][1][4 * lane])[0] = make_float4(Vxy[4], Vxy[5], Vxy[6], Vxy[7]);
            __builtin_amdgcn_wave_barrier();

            float h[5][8];
            // lo1 = cols c0+8..11, hi1 = c0+12..15, lo2 = c0+16..19 (zeros past 511)
#define HORIZ(Q, VA)                                                           \
            {                                                                  \
                const float4 lo1 = *(const float4*)&H[Q][0][4 * lane + 4];     \
                const float4 hi1 = *(const float4*)&H[Q][1][4 * lane + 4];     \
                const float4 lo2 = *(const float4*)&H[Q][0][4 * lane + 8];     \
                float s = ((VA[0] + VA[1]) + (VA[2] + VA[3]))                  \
                        + ((VA[4] + VA[5]) + (VA[6] + VA[7]));                 \
                s += (lo1.x + lo1.y) + lo1.z;                                  \
                h[Q][0] = s;                                                   \
                s += lo1.w - VA[0]; h[Q][1] = s;                               \
                s += hi1.x - VA[1]; h[Q][2] = s;                               \
                s += hi1.y - VA[2]; h[Q][3] = s;                               \
                s += hi1.z - VA[3]; h[Q][4] = s;                               \
                s += hi1.w - VA[4]; h[Q][5] = s;                               \
                s += lo2.x - VA[5]; h[Q][6] = s;                               \
                s += lo2.y - VA[6]; h[Q][7] = s;                               \
            }
            HORIZ(0, Vx)
            HORIZ(1, Vy)
            HORIZ(2, Vxx)
            HORIZ(3, Vyy)
            HORIZ(4, Vxy)
#undef HORIZ

#pragma unroll
            for (int j = 0; j < 8; ++j) {
                if (c0 + j < OUTW) {
                    const float X  = h[0][j], Y  = h[1][j];
                    const float XX = h[2][j], YY = h[3][j], XY = h[4][j];
                    const float x2 = X * X, y2 = Y * Y, xy = X * Y;
                    // scaled domain: everything multiplied by 121^2
                    const float A  = fmaf(2.f, xy, C1S);
                    const float B  = fmaf(2.f, fmaf(121.f, XY, -xy), C2S);
                    const float Cc = x2 + y2 + C1S;
                    const float sx = fmaxf(fmaf(121.f, XX, -x2), 0.f);
                    const float sy = fmaxf(fmaf(121.f, YY, -y2), 0.f);
                    const float D  = (sx + sy) + C2S;
                    const float den = fmaf(Cc, D, EPS4);
                    float rr = __builtin_amdgcn_rcpf(den);
                    rr = rr * (2.f - den * rr);       // 1 Newton step
                    lsum = fmaf(A * B, rr, lsum);
                }
            }
        }

        // ---- rotate pipelines ----
        nx0 = nX0; nx1 = nX1; ny0 = nY0; ny1 = nY1;
        ox0 = oX0; ox1 = oX1; oy0 = oY0; oy1 = oY1;
    }

    // ---- wave reduction -> partials ----
#pragma unroll
    for (int off = 32; off > 0; off >>= 1) lsum += __shfl_down(lsum, off, 64);
    if (lane == 0) {
        if (mode == 0) part[plane * NSEG + seg] = (double)lsum;
        else           atomicAdd(part, (double)lsum);
    }
}

__global__ __launch_bounds__(256) void ssim_final(const double* __restrict__ part,
                                                  int n, float* __restrict__ out) {
    __shared__ double s[4];
    double v = 0.0;
    for (int i = threadIdx.x; i < n; i += 256) v += part[i];
#pragma unroll
    for (int off = 32; off > 0; off >>= 1) v += __shfl_down(v, off, 64);
    if ((threadIdx.x & 63) == 0) s[threadIdx.x >> 6] = v;
    __syncthreads();
    if (threadIdx.x == 0) {
        double tot = (s[0] + s[1]) + (s[2] + s[3]);
        const double N = (double)NPLANES * OUTW * OUTW;   // 12,096,192
        out[0] = 1.0f - (float)(tot / N);
    }
}

extern "C" void kernel_launch(void* const* d_in, const int* in_sizes, int n_in,
                              void* d_out, int out_size, void* d_ws, size_t ws_size,
                              hipStream_t stream) {
    const float* x = (const float*)d_in[0];
    const float* y = (const float*)d_in[1];
    float* out = (float*)d_out;
    double* part = (double*)d_ws;

    if (ws_size >= (size_t)NPART * sizeof(double)) {
        ssim_main<<<dim3(NSEG, NPLANES), dim3(64), 0, stream>>>(x, y, part, 0);
        ssim_final<<<dim3(1), dim3(256), 0, stream>>>(part, NPART, out);
    } else {
        ssim_zero<<<dim3(1), dim3(64), 0, stream>>>(part);
        ssim_main<<<dim3(NSEG, NPLANES), dim3(64), 0, stream>>>(x, y, part, 1);
        ssim_final<<<dim3(1), dim3(256), 0, stream>>>(part, 1, out);
    }
}

// Round 6
// 142.310 us; speedup vs baseline: 1.0538x; 1.0538x over previous
//
#include <hip/hip_runtime.h>

// PooledSSIMLoss: x,y (16,3,512,512) fp32, 11x11 VALID box filters,
// SSIM map (48,502,502) -> scalar 1 - mean.
//
// R5 (resubmit; previous round hit GPUAcquisitionTimeout): lane-autonomous.
// No LDS, no barriers, no shuffles (except final reduce). Each lane owns 8
// output cols and keeps vertical running sums V* for its full 18-col
// horizontal window (10 halo cols loaded redundantly from global; L1/L2-
// served). Horizontal 11-tap is a pure in-register sliding sum. Old row
// (r-11) re-fetched from global (L2-hot). New and old rows prefetched one
// iteration ahead. XCD-aware block swizzle keeps each plane's segments on
// one XCD for halo L2 reuse.

#define WIN     11
#define IMG     512
#define PLSZ    (IMG * IMG)
#define OUTW    502
#define SEG     12
#define NSEG    42             // ceil(502/12)
#define NPLANES 48
#define NBLK    (NSEG * NPLANES)   // 2016

#define C1S   1.4641f          // (0.01)^2 * 121^2
#define C2S   13.1769f         // (0.03)^2 * 121^2
#define EPS4  2.1434881f       // 1e-8 * 121^4

__global__ __launch_bounds__(64) void ssim_zero(double* acc) {
    if (threadIdx.x == 0) acc[0] = 0.0;
}

__global__ __launch_bounds__(64, 2) void ssim_main(const float* __restrict__ x,
                                                   const float* __restrict__ y,
                                                   double* __restrict__ part,
                                                   int mode) {
    const int lane = threadIdx.x;          // 0..63
    const int id   = blockIdx.x;           // 0..2015
    // XCD swizzle: id%8 ~ XCD; give each plane a fixed XCD residue.
    const int q8    = id >> 3;             // 0..251
    const int plane = (id & 7) + 8 * (q8 / NSEG);   // 0..47
    const int seg   = q8 % NSEG;                    // 0..41

    const int o0 = seg * SEG;
    const int o1 = (o0 + SEG < OUTW) ? (o0 + SEG) : OUTW;
    const int r0 = o0;
    const int r1 = o1 + WIN - 2;           // <= 511

    const int c0 = 8 * lane;               // first output col of this lane
    // window cols c0..c0+17; clamp in-row (clamped lanes feed masked outputs)
    const int a0 = c0;
    const int a1 = c0 + 4;
    const int a2 = (c0 + 8  < 508) ? (c0 + 8)  : 508;
    const int a3 = (c0 + 12 < 508) ? (c0 + 12) : 508;
    const int a4 = (c0 + 16 < 510) ? (c0 + 16) : 510;

    const float* xp = x + plane * PLSZ;
    const float* yp = y + plane * PLSZ;

#define LOADROW(P, R, v0, v1, v2, v3, v4)                        \
    { const float* rp_ = (P) + ((R) << 9);                       \
      v0 = *(const float4*)(rp_ + a0);                           \
      v1 = *(const float4*)(rp_ + a1);                           \
      v2 = *(const float4*)(rp_ + a2);                           \
      v3 = *(const float4*)(rp_ + a3);                           \
      v4 = *(const float2*)(rp_ + a4); }

#define UNPACK(v0, v1, v2, v3, v4, arr)                          \
    { arr[0]=v0.x;  arr[1]=v0.y;  arr[2]=v0.z;  arr[3]=v0.w;     \
      arr[4]=v1.x;  arr[5]=v1.y;  arr[6]=v1.z;  arr[7]=v1.w;     \
      arr[8]=v2.x;  arr[9]=v2.y;  arr[10]=v2.z; arr[11]=v2.w;    \
      arr[12]=v3.x; arr[13]=v3.y; arr[14]=v3.z; arr[15]=v3.w;    \
      arr[16]=v4.x; arr[17]=v4.y; }

    float Vx[18], Vy[18], Vxx[18], Vyy[18], Vxy[18];
#pragma unroll
    for (int j = 0; j < 18; ++j) {
        Vx[j] = 0.f; Vy[j] = 0.f; Vxx[j] = 0.f; Vyy[j] = 0.f; Vxy[j] = 0.f;
    }

    const float4 z4 = make_float4(0.f, 0.f, 0.f, 0.f);
    const float2 z2 = make_float2(0.f, 0.f);
    // current-new (row r), current-old (row r-11), and in-flight next of each
    float4 cnx0, cnx1, cnx2, cnx3; float2 cnx4;
    float4 cny0, cny1, cny2, cny3; float2 cny4;
    float4 cox0 = z4, cox1 = z4, cox2 = z4, cox3 = z4; float2 cox4 = z2;
    float4 coy0 = z4, coy1 = z4, coy2 = z4, coy3 = z4; float2 coy4 = z2;
    float4 nnx0 = z4, nnx1 = z4, nnx2 = z4, nnx3 = z4; float2 nnx4 = z2;
    float4 nny0 = z4, nny1 = z4, nny2 = z4, nny3 = z4; float2 nny4 = z2;
    float4 nox0 = z4, nox1 = z4, nox2 = z4, nox3 = z4; float2 nox4 = z2;
    float4 noy0 = z4, noy1 = z4, noy2 = z4, noy3 = z4; float2 noy4 = z2;

    LOADROW(xp, r0, cnx0, cnx1, cnx2, cnx3, cnx4)
    LOADROW(yp, r0, cny0, cny1, cny2, cny3, cny4)

    float lsum = 0.f;

    for (int r = r0; r <= r1; ++r) {
        // ---- issue next-iteration loads (consumed at iter r+1) ----
        if (r < r1) {
            LOADROW(xp, r + 1, nnx0, nnx1, nnx2, nnx3, nnx4)
            LOADROW(yp, r + 1, nny0, nny1, nny2, nny3, nny4)
        }
        const int ro = r + 1 - WIN;        // old row subtracted at iter r+1
        if (ro >= r0) {
            LOADROW(xp, ro, nox0, nox1, nox2, nox3, nox4)
            LOADROW(yp, ro, noy0, noy1, noy2, noy3, noy4)
        }

        // ---- vertical running sums: add new row r ----
        {
            float xn[18], yn[18];
            UNPACK(cnx0, cnx1, cnx2, cnx3, cnx4, xn)
            UNPACK(cny0, cny1, cny2, cny3, cny4, yn)
#pragma unroll
            for (int j = 0; j < 18; ++j) {
                Vx[j] += xn[j];
                Vy[j] += yn[j];
                Vxx[j] = fmaf(xn[j], xn[j], Vxx[j]);
                Vyy[j] = fmaf(yn[j], yn[j], Vyy[j]);
                Vxy[j] = fmaf(xn[j], yn[j], Vxy[j]);
            }
        }
        // ---- subtract old row r-11 ----
        if (r - r0 >= WIN) {
            float xo[18], yo[18];
            UNPACK(cox0, cox1, cox2, cox3, cox4, xo)
            UNPACK(coy0, coy1, coy2, coy3, coy4, yo)
#pragma unroll
            for (int j = 0; j < 18; ++j) {
                Vx[j] -= xo[j];
                Vy[j] -= yo[j];
                Vxx[j] = fmaf(-xo[j], xo[j], Vxx[j]);
                Vyy[j] = fmaf(-yo[j], yo[j], Vyy[j]);
                Vxy[j] = fmaf(-xo[j], yo[j], Vxy[j]);
            }
        }

        // ---- emission: in-register horizontal 11-tap + SSIM, row r-10 ----
        if (r - r0 >= WIN - 1) {
#define SUM11(V, s)                                                       \
            { float t0_ = V[0] + V[1], t1_ = V[2] + V[3];                 \
              float t2_ = V[4] + V[5], t3_ = V[6] + V[7];                 \
              float t4_ = V[8] + V[9];                                    \
              s = ((t0_ + t1_) + (t2_ + t3_)) + (t4_ + V[10]); }
            float s0, s1, s2, s3, s4;
            SUM11(Vx,  s0)
            SUM11(Vy,  s1)
            SUM11(Vxx, s2)
            SUM11(Vyy, s3)
            SUM11(Vxy, s4)
#undef SUM11
#pragma unroll
            for (int j = 0; j < 8; ++j) {
                const float X = s0, Y = s1, XX = s2, YY = s3, XY = s4;
                const float x2 = X * X, y2 = Y * Y, xy = X * Y;
                // scaled domain: all quantities carry a 121^2 factor
                const float A  = fmaf(2.f, xy, C1S);
                const float B  = fmaf(2.f, fmaf(121.f, XY, -xy), C2S);
                const float Cc = (x2 + y2) + C1S;
                const float sx = fmaxf(fmaf(121.f, XX, -x2), 0.f);
                const float sy = fmaxf(fmaf(121.f, YY, -y2), 0.f);
                const float D  = (sx + sy) + C2S;
                const float den = fmaf(Cc, D, EPS4);
                float rr = __builtin_amdgcn_rcpf(den);
                rr = rr * (2.f - den * rr);            // 1 Newton step
                if (c0 + j < OUTW) lsum = fmaf(A * B, rr, lsum);
                if (j < 7) {
                    s0 += Vx[j + 11]  - Vx[j];
                    s1 += Vy[j + 11]  - Vy[j];
                    s2 += Vxx[j + 11] - Vxx[j];
                    s3 += Vyy[j + 11] - Vyy[j];
                    s4 += Vxy[j + 11] - Vxy[j];
                }
            }
        }

        // ---- rotate pipelines ----
        cnx0 = nnx0; cnx1 = nnx1; cnx2 = nnx2; cnx3 = nnx3; cnx4 = nnx4;
        cny0 = nny0; cny1 = nny1; cny2 = nny2; cny3 = nny3; cny4 = nny4;
        cox0 = nox0; cox1 = nox1; cox2 = nox2; cox3 = nox3; cox4 = nox4;
        coy0 = noy0; coy1 = noy1; coy2 = noy2; coy3 = noy3; coy4 = noy4;
    }
#undef LOADROW
#undef UNPACK

    // ---- wave reduction -> partials ----
#pragma unroll
    for (int off = 32; off > 0; off >>= 1) lsum += __shfl_down(lsum, off, 64);
    if (lane == 0) {
        if (mode == 0) part[id] = (double)lsum;
        else           atomicAdd(part, (double)lsum);
    }
}

__global__ __launch_bounds__(256) void ssim_final(const double* __restrict__ part,
                                                  int n, float* __restrict__ out) {
    __shared__ double s[4];
    double v = 0.0;
    for (int i = threadIdx.x; i < n; i += 256) v += part[i];
#pragma unroll
    for (int off = 32; off > 0; off >>= 1) v += __shfl_down(v, off, 64);
    if ((threadIdx.x & 63) == 0) s[threadIdx.x >> 6] = v;
    __syncthreads();
    if (threadIdx.x == 0) {
        double tot = (s[0] + s[1]) + (s[2] + s[3]);
        const double N = (double)NPLANES * OUTW * OUTW;   // 12,096,192
        out[0] = 1.0f - (float)(tot / N);
    }
}

extern "C" void kernel_launch(void* const* d_in, const int* in_sizes, int n_in,
                              void* d_out, int out_size, void* d_ws, size_t ws_size,
                              hipStream_t stream) {
    const float* x = (const float*)d_in[0];
    const float* y = (const float*)d_in[1];
    float* out = (float*)d_out;
    double* part = (double*)d_ws;

    if (ws_size >= (size_t)NBLK * sizeof(double)) {
        ssim_main<<<dim3(NBLK), dim3(64), 0, stream>>>(x, y, part, 0);
        ssim_final<<<dim3(1), dim3(256), 0, stream>>>(part, NBLK, out);
    } else {
        ssim_zero<<<dim3(1), dim3(64), 0, stream>>>(part);
        ssim_main<<<dim3(NBLK), dim3(64), 0, stream>>>(x, y, part, 1);
        ssim_final<<<dim3(1), dim3(256), 0, stream>>>(part, 1, out);
    }
}